// Round 12
// baseline (163.241 us; speedup 1.0000x reference)
//
#include <hip/hip_runtime.h>
#include <math.h>

typedef _Float16 half_t;
typedef _Float16 half8 __attribute__((ext_vector_type(8)));
typedef unsigned short ushort_t;

#define BATCH 4096
#define SEQL  512
#define NF    32
#define DEMB  8
#define DOUT  64

// windows: ks=2,3,4,5 -> 25,125,625,3125 rows; concat offsets 0,25,150,775
#define NWIN_TOTAL 3900
#define ZROW       3900    // zero-sentinel row id for tail positions
#define HWIN_OFF   4096    // float idx: fp16 h-table (3900*32 half)
#define TOFF       70000   // float idx: tap table T[14][5][32]
#define EHE_OFF    131072  // float idx (byte 524288): EHE table, 3901 rows x 128 B
#define MSHIFT     8.0f    // static softmax shift (> any achievable score max)

__device__ __forceinline__ float gelu_exact(float x) {
    return 0.5f * x * (1.0f + erff(x * 0.70710678118654752f));
}

// Stage A: tap table. T[tapg][d][f] = sum_c emb[d][c] * cw[f][c][t]
__global__ __launch_bounds__(256) void precompute_taps(
    const float* __restrict__ emb,
    const float* __restrict__ cw0, const float* __restrict__ cw1,
    const float* __restrict__ cw2, const float* __restrict__ cw3,
    float* __restrict__ ws)
{
    const int gid = blockIdx.x * blockDim.x + threadIdx.x;
    if (gid >= 14 * 5 * NF) return;
    const int f = gid & 31;
    const int r = gid >> 5;          // 0..69
    const int tapg = r / 5;
    const int d    = r % 5;

    int ks, t; const float* cw;
    if (tapg < 2)      { ks = 2; cw = cw0; t = tapg; }
    else if (tapg < 5) { ks = 3; cw = cw1; t = tapg - 2; }
    else if (tapg < 9) { ks = 4; cw = cw2; t = tapg - 5; }
    else               { ks = 5; cw = cw3; t = tapg - 9; }

    const float* e = emb + d * DEMB;
    float s = 0.0f;
#pragma unroll
    for (int c = 0; c < DEMB; ++c)
        s += e[c] * cw[(f * DEMB + c) * ks + t];
    ws[TOFF + r * NF + f] = s;
}

// Stage B: window table via tap table — coalesced reads only.
// Writes fp16 h-table (HWIN_OFF) and fp32 scores (ws[0..3899]).
__global__ __launch_bounds__(256) void precompute_windows(
    const float* __restrict__ cb0, const float* __restrict__ aw0, const float* __restrict__ ab0,
    const float* __restrict__ cb1, const float* __restrict__ aw1, const float* __restrict__ ab1,
    const float* __restrict__ cb2, const float* __restrict__ aw2, const float* __restrict__ ab2,
    const float* __restrict__ cb3, const float* __restrict__ aw3, const float* __restrict__ ab3,
    float* __restrict__ ws)
{
    const int gid = blockIdx.x * blockDim.x + threadIdx.x;
    if (gid >= NWIN_TOTAL * NF) return;
    const int wgid = gid >> 5;
    const int f    = gid & 31;

    int w, ks, cum;
    const float *cb, *aw, *ab;
    if (wgid < 25)       { w = wgid;       ks = 2; cum = 0; cb = cb0; aw = aw0; ab = ab0; }
    else if (wgid < 150) { w = wgid - 25;  ks = 3; cum = 2; cb = cb1; aw = aw1; ab = ab1; }
    else if (wgid < 775) { w = wgid - 150; ks = 4; cum = 5; cb = cb2; aw = aw2; ab = ab2; }
    else                 { w = wgid - 775; ks = 5; cum = 9; cb = cb3; aw = aw3; ab = ab3; }

    float h = cb[f];
    int ww = w;
    for (int t = ks - 1; t >= 0; --t) {
        int d = ww % 5; ww /= 5;
        h += ws[TOFF + ((cum + t) * 5 + d) * NF + f];
    }
    float g = gelu_exact(h);
    ((half_t*)(ws + HWIN_OFF))[wgid * NF + f] = (half_t)g;

    float s = g * aw[f];
#pragma unroll
    for (int off = 16; off; off >>= 1) s += __shfl_xor(s, off, 32);
    if (f == 0) ws[wgid] = s + ab[0];
}

// Stage C: EHE table. Row gid (128 B): [ E*h (32 fp16) | E (fp32) | pad ].
// Row ZROW is all zeros (tail sentinel). One thread per (row, 16B-seg).
__global__ __launch_bounds__(256) void finalize_ehe(float* __restrict__ ws)
{
    const int gid = blockIdx.x * blockDim.x + threadIdx.x;
    if (gid >= (NWIN_TOTAL + 1) * 8) return;
    const int row = gid >> 3;
    const int seg = gid & 7;

    float4 v = {0.f, 0.f, 0.f, 0.f};
    if (row < NWIN_TOTAL) {
        const float E = __expf(ws[row] - MSHIFT);
        if (seg < 4) {
            const half_t* h = (const half_t*)(ws + HWIN_OFF) + row * NF + seg * 8;
            half_t o[8];
#pragma unroll
            for (int j = 0; j < 8; ++j) o[j] = (half_t)(E * (float)h[j]);
            v = *(const float4*)o;
        } else if (seg == 4) {
            v.x = E;
        }
    }
    *(float4*)((char*)(ws + EHE_OFF) + row * 128 + seg * 16) = v;
}

__global__ __launch_bounds__(256) void fused_main(
    const int*   __restrict__ xidx,
    const float* __restrict__ ws,
    const float* __restrict__ projw, const float* __restrict__ projb,
    const float* __restrict__ gamma, const float* __restrict__ beta,
    float* __restrict__ out)
{
    __shared__ int      xs[SEQL];        // 2 KB
    __shared__ ushort_t pwid[4][SEQL];   // 4 KB  global row ids (sentinel for tail)
    __shared__ float    feat[4 * NF];    // 0.5 KB

    const int b   = blockIdx.x;
    const int tid = threadIdx.x;

#pragma unroll
    for (int i = tid; i < SEQL / 4; i += 256)
        ((int4*)xs)[i] = ((const int4*)(xidx + b * SEQL))[i];
    __syncthreads();

    const int wave = tid >> 6;
    const int lane = tid & 63;

    constexpr int KS[4]  = {2, 3, 4, 5};
    constexpr int SWB[4] = {0, 25, 150, 775};

    const int ks = KS[wave];
    const int Lp = SEQL + 1 - ks;

    // ---- pass 1: window ids only (no gather, no softmax) ----
#pragma unroll
    for (int it = 0; it < 8; ++it) {
        const int l = lane + it * 64;
        ushort_t v = ZROW;
        if (l < Lp) {
            int w = xs[l];
            for (int t = 1; t < ks; ++t) w = w * 5 + xs[l + t];
            v = (ushort_t)(SWB[wave] + w);
        }
        pwid[wave][l] = v;
    }
    __syncthreads();

    // ---- pass 2: single-stream gather-accumulate over 128 B EHE rows ----
    // 8 lanes per row: lanes r=0..3 take E*h quads, lane r=4 takes E (denominator).
    const int r = lane & 7;
    const int o = lane >> 3;
    const int seg = (r < 4) ? r : 4;
    const char* base = (const char*)(ws + EHE_OFF) + seg * 16;

    float a[8];
#pragma unroll
    for (int j = 0; j < 8; ++j) a[j] = 0.0f;
    float den = 0.0f;

#pragma unroll 8
    for (int it = 0; it < 64; ++it) {
        const int pos = it * 8 + o;
        const int gid = pwid[wave][pos];
        const float4 rv = *(const float4*)(base + gid * 128);   // 1 line/row
        if (r < 4) {
            const half8 hv = *(const half8*)&rv;
#pragma unroll
            for (int j = 0; j < 8; ++j) a[j] += (float)hv[j];
        } else if (r == 4) {
            den += rv.x;
        }
    }

#pragma unroll
    for (int off = 8; off < 64; off <<= 1) {
#pragma unroll
        for (int j = 0; j < 8; ++j) a[j] += __shfl_xor(a[j], off);
        den += __shfl_xor(den, off);
    }
    const float dtot = __shfl(den, 4);   // lane 4 holds the reduced denominator
    if (lane < 4) {
        const float inv = 1.0f / dtot;
        float* fp = feat + wave * NF + lane * 8;
#pragma unroll
        for (int j = 0; j < 8; ++j) fp[j] = a[j] * inv;
    }
    __syncthreads();

    // ---- projection + GELU + LayerNorm (wave 0) ----
    if (tid < DOUT) {
        float z = projb[tid];
        const float4* pwr = (const float4*)(projw + tid * (4 * NF));
#pragma unroll
        for (int q = 0; q < 32; ++q) {
            float4 wq = pwr[q];
            const float* fj = feat + q * 4;
            z += wq.x * fj[0] + wq.y * fj[1] + wq.z * fj[2] + wq.w * fj[3];
        }
        z = gelu_exact(z);

        float s1 = z, s2 = z * z;
#pragma unroll
        for (int off = 32; off; off >>= 1) {
            s1 += __shfl_xor(s1, off);
            s2 += __shfl_xor(s2, off);
        }
        const float mu  = s1 * (1.0f / 64.0f);
        const float var = s2 * (1.0f / 64.0f) - mu * mu;
        const float rr  = rsqrtf(var + 1e-5f);
        out[b * DOUT + tid] = (z - mu) * rr * gamma[tid] + beta[tid];
    }
}

extern "C" void kernel_launch(void* const* d_in, const int* in_sizes, int n_in,
                              void* d_out, int out_size, void* d_ws, size_t ws_size,
                              hipStream_t stream) {
    const int*   xidx = (const int*)d_in[0];
    const float* emb  = (const float*)d_in[1];
    const float* cw[4]; const float* cb[4]; const float* aw[4]; const float* ab[4];
    for (int i = 0; i < 4; ++i) {
        cw[i] = (const float*)d_in[2 + 4 * i];
        cb[i] = (const float*)d_in[3 + 4 * i];
        aw[i] = (const float*)d_in[4 + 4 * i];
        ab[i] = (const float*)d_in[5 + 4 * i];
    }
    const float* projw = (const float*)d_in[18];
    const float* projb = (const float*)d_in[19];
    const float* gm    = (const float*)d_in[20];
    const float* bt    = (const float*)d_in[21];
    float* ws  = (float*)d_ws;
    float* out = (float*)d_out;

    hipLaunchKernelGGL(precompute_taps, dim3((14 * 5 * NF + 255) / 256), dim3(256), 0, stream,
                       emb, cw[0], cw[1], cw[2], cw[3], ws);

    hipLaunchKernelGGL(precompute_windows, dim3((NWIN_TOTAL * NF + 255) / 256), dim3(256), 0, stream,
                       cb[0], aw[0], ab[0],
                       cb[1], aw[1], ab[1],
                       cb[2], aw[2], ab[2],
                       cb[3], aw[3], ab[3],
                       ws);

    hipLaunchKernelGGL(finalize_ehe, dim3(((NWIN_TOTAL + 1) * 8 + 255) / 256), dim3(256), 0, stream,
                       ws);

    hipLaunchKernelGGL(fused_main, dim3(BATCH), dim3(256), 0, stream,
                       xidx, ws, projw, projb, gm, bt, out);
}

// Round 14
// 146.418 us; speedup vs baseline: 1.1149x; 1.1149x over previous
//
#include <hip/hip_runtime.h>
#include <math.h>

typedef _Float16 half_t;
typedef _Float16 half8 __attribute__((ext_vector_type(8)));
typedef unsigned short ushort_t;

#define BATCH 4096
#define SEQL  512
#define NF    32
#define DEMB  8
#define DOUT  64

// windows: ks=2,3,4,5 -> 25,125,625,3125 rows; concat offsets 0,25,150,775
#define NWIN_TOTAL 3900
#define HWIN_OFF   4096    // float idx: fp16 h-table, 3900*32 half (ends 66496)
#define ETAB_OFF   67000   // float idx: fp16 E-table, 3900 half (E = exp(score-8))
#define TOFF       70000   // float idx: tap table T[14][5][32]
#define EHE_OFF    131072  // float idx (byte 524288, 256-aligned): combined table, 3125 x 256 B
#define MSHIFT     8.0f    // static softmax shift (validated in R12: absmax 0.0156)

__device__ __forceinline__ float gelu_exact(float x) {
    return 0.5f * x * (1.0f + erff(x * 0.70710678118654752f));
}

// Stage A: tap table. T[tapg][d][f] = sum_c emb[d][c] * cw[f][c][t]
__global__ __launch_bounds__(256) void precompute_taps(
    const float* __restrict__ emb,
    const float* __restrict__ cw0, const float* __restrict__ cw1,
    const float* __restrict__ cw2, const float* __restrict__ cw3,
    float* __restrict__ ws)
{
    const int gid = blockIdx.x * blockDim.x + threadIdx.x;
    if (gid >= 14 * 5 * NF) return;
    const int f = gid & 31;
    const int r = gid >> 5;          // 0..69
    const int tapg = r / 5;
    const int d    = r % 5;

    int ks, t; const float* cw;
    if (tapg < 2)      { ks = 2; cw = cw0; t = tapg; }
    else if (tapg < 5) { ks = 3; cw = cw1; t = tapg - 2; }
    else if (tapg < 9) { ks = 4; cw = cw2; t = tapg - 5; }
    else               { ks = 5; cw = cw3; t = tapg - 9; }

    const float* e = emb + d * DEMB;
    float s = 0.0f;
#pragma unroll
    for (int c = 0; c < DEMB; ++c)
        s += e[c] * cw[(f * DEMB + c) * ks + t];
    ws[TOFF + r * NF + f] = s;
}

// Stage B: per-window h-table (fp16) + E-table (fp16, exp(score-MSHIFT)).
__global__ __launch_bounds__(256) void precompute_windows(
    const float* __restrict__ cb0, const float* __restrict__ aw0, const float* __restrict__ ab0,
    const float* __restrict__ cb1, const float* __restrict__ aw1, const float* __restrict__ ab1,
    const float* __restrict__ cb2, const float* __restrict__ aw2, const float* __restrict__ ab2,
    const float* __restrict__ cb3, const float* __restrict__ aw3, const float* __restrict__ ab3,
    float* __restrict__ ws)
{
    const int gid = blockIdx.x * blockDim.x + threadIdx.x;
    if (gid >= NWIN_TOTAL * NF) return;
    const int wgid = gid >> 5;
    const int f    = gid & 31;

    int w, ks, cum;
    const float *cb, *aw, *ab;
    if (wgid < 25)       { w = wgid;       ks = 2; cum = 0; cb = cb0; aw = aw0; ab = ab0; }
    else if (wgid < 150) { w = wgid - 25;  ks = 3; cum = 2; cb = cb1; aw = aw1; ab = ab1; }
    else if (wgid < 775) { w = wgid - 150; ks = 4; cum = 5; cb = cb2; aw = aw2; ab = ab2; }
    else                 { w = wgid - 775; ks = 5; cum = 9; cb = cb3; aw = aw3; ab = ab3; }

    float h = cb[f];
    int ww = w;
    for (int t = ks - 1; t >= 0; --t) {
        int d = ww % 5; ww /= 5;
        h += ws[TOFF + ((cum + t) * 5 + d) * NF + f];
    }
    float g = gelu_exact(h);
    ((half_t*)(ws + HWIN_OFF))[wgid * NF + f] = (half_t)g;

    float s = g * aw[f];
#pragma unroll
    for (int off = 16; off; off >>= 1) s += __shfl_xor(s, off, 32);
    if (f == 0)
        ((half_t*)(ws + ETAB_OFF))[wgid] = (half_t)__expf(s + ab[0] - MSHIFT);
}

// Stage C: combined 5-gram table. Row w5 (256 B): [E2*h2 |E3*h3 |E4*h4 |E5*h5],
// each block 32 fp16, branch c uses prefix window w5 / 5^(3-c).
__global__ __launch_bounds__(256) void build_combined(float* __restrict__ ws)
{
    const int gid = blockIdx.x * blockDim.x + threadIdx.x;
    if (gid >= 3125 * 16) return;
    const int w5  = gid >> 4;
    const int seg = gid & 15;
    const int c   = seg >> 2;
    const int q   = seg & 3;

    int wc, swb;
    if (c == 0)      { wc = w5 / 125; swb = 0;   }
    else if (c == 1) { wc = w5 / 25;  swb = 25;  }
    else if (c == 2) { wc = w5 / 5;   swb = 150; }
    else             { wc = w5;       swb = 775; }
    const int gw = swb + wc;

    const float E = (float)((const half_t*)(ws + ETAB_OFF))[gw];
    const half_t* hp = (const half_t*)(ws + HWIN_OFF) + gw * NF + q * 8;
    half_t o[8];
#pragma unroll
    for (int j = 0; j < 8; ++j) o[j] = (half_t)(E * (float)hp[j]);
    *(float4*)((char*)(ws + EHE_OFF) + w5 * 256 + seg * 16) = *(const float4*)o;
}

__global__ __launch_bounds__(256) void fused_main(
    const int*   __restrict__ xidx,
    const float* __restrict__ ws,
    const float* __restrict__ projw, const float* __restrict__ projb,
    const float* __restrict__ gamma, const float* __restrict__ beta,
    float* __restrict__ out)
{
    __shared__ int      xs[SEQL + 8];     // tokens + zero pad
    __shared__ ushort_t pwid[SEQL];       // 5-gram id per position (1 KB)
    __shared__ float    partial[4][16][8];
    __shared__ float    redD[4][4];
    __shared__ float    feat[4 * NF];

    const int b   = blockIdx.x;
    const int tid = threadIdx.x;

#pragma unroll
    for (int i = tid; i < SEQL / 4; i += 256)
        ((int4*)xs)[i] = ((const int4*)(xidx + b * SEQL))[i];
    if (tid < 8) xs[SEQL + tid] = 0;
    __syncthreads();

    const int wave = tid >> 6;
    const int lane = tid & 63;
    const half_t* Etab = (const half_t*)(ws + ETAB_OFF);

    // ---- pass 1: 5-gram ids + denominator accumulation (no softmax!) ----
    float den0 = 0.f, den1 = 0.f, den2 = 0.f, den3 = 0.f;
#pragma unroll
    for (int it = 0; it < 2; ++it) {
        const int l = wave * 128 + it * 64 + lane;
        const int w2 = xs[l] * 5 + xs[l + 1];
        const int w3 = w2 * 5 + xs[l + 2];
        const int w4 = w3 * 5 + xs[l + 3];
        const int w5 = w4 * 5 + xs[l + 4];
        pwid[l] = (ushort_t)w5;
        if (l < 511) den0 += (float)Etab[w2];          // L1-resident 7.8 KB table
        if (l < 510) den1 += (float)Etab[25 + w3];
        if (l < 509) den2 += (float)Etab[150 + w4];
        if (l < 508) den3 += (float)Etab[775 + w5];
    }
#pragma unroll
    for (int off = 32; off; off >>= 1) {
        den0 += __shfl_xor(den0, off);
        den1 += __shfl_xor(den1, off);
        den2 += __shfl_xor(den2, off);
        den3 += __shfl_xor(den3, off);
    }
    if (lane == 0) {
        redD[wave][0] = den0; redD[wave][1] = den1;
        redD[wave][2] = den2; redD[wave][3] = den3;
    }
    __syncthreads();

    // ---- pass 2: single-stream gather, 16 lanes x 256 B row, 4 positions/instr ----
    const int seg = lane & 15;       // (branch c = seg>>2, quad q = seg&3)
    const int o   = lane >> 4;       // position within group of 4
    const int c   = seg >> 2;
    const int Lpc = 511 - c;
    const char* base = (const char*)(ws + EHE_OFF) + seg * 16;

    float a[8];
#pragma unroll
    for (int j = 0; j < 8; ++j) a[j] = 0.0f;

#pragma unroll 8
    for (int it = 0; it < 32; ++it) {
        const int pos = wave * 128 + it * 4 + o;
        const int w5 = pwid[pos];                       // LDS broadcast per group
        if (pos < Lpc) {
            const float4 rv = *(const float4*)(base + w5 * 256);  // coalesced 256 B/group
            const half8 hv = *(const half8*)&rv;
#pragma unroll
            for (int j = 0; j < 8; ++j) a[j] += (float)hv[j];
        }
    }

#pragma unroll
    for (int j = 0; j < 8; ++j) {
        a[j] += __shfl_xor(a[j], 16);
        a[j] += __shfl_xor(a[j], 32);
    }
    if (lane < 16) {
#pragma unroll
        for (int j = 0; j < 8; ++j) partial[wave][lane][j] = a[j];
    }
    __syncthreads();

    if (tid < 128) {
        const int sg = tid >> 3, j = tid & 7, cc = tid >> 5;
        const float d = redD[0][cc] + redD[1][cc] + redD[2][cc] + redD[3][cc];
        feat[tid] = (partial[0][sg][j] + partial[1][sg][j]
                   + partial[2][sg][j] + partial[3][sg][j]) / d;
    }
    __syncthreads();

    // ---- projection + GELU + LayerNorm (wave 0) ----
    if (tid < DOUT) {
        float z = projb[tid];
        const float4* pwr = (const float4*)(projw + tid * (4 * NF));
#pragma unroll
        for (int q = 0; q < 32; ++q) {
            float4 wq = pwr[q];
            const float* fj = feat + q * 4;
            z += wq.x * fj[0] + wq.y * fj[1] + wq.z * fj[2] + wq.w * fj[3];
        }
        z = gelu_exact(z);

        float s1 = z, s2 = z * z;
#pragma unroll
        for (int off = 32; off; off >>= 1) {
            s1 += __shfl_xor(s1, off);
            s2 += __shfl_xor(s2, off);
        }
        const float mu  = s1 * (1.0f / 64.0f);
        const float var = s2 * (1.0f / 64.0f) - mu * mu;
        const float rr  = rsqrtf(var + 1e-5f);
        out[b * DOUT + tid] = (z - mu) * rr * gamma[tid] + beta[tid];
    }
}

extern "C" void kernel_launch(void* const* d_in, const int* in_sizes, int n_in,
                              void* d_out, int out_size, void* d_ws, size_t ws_size,
                              hipStream_t stream) {
    const int*   xidx = (const int*)d_in[0];
    const float* emb  = (const float*)d_in[1];
    const float* cw[4]; const float* cb[4]; const float* aw[4]; const float* ab[4];
    for (int i = 0; i < 4; ++i) {
        cw[i] = (const float*)d_in[2 + 4 * i];
        cb[i] = (const float*)d_in[3 + 4 * i];
        aw[i] = (const float*)d_in[4 + 4 * i];
        ab[i] = (const float*)d_in[5 + 4 * i];
    }
    const float* projw = (const float*)d_in[18];
    const float* projb = (const float*)d_in[19];
    const float* gm    = (const float*)d_in[20];
    const float* bt    = (const float*)d_in[21];
    float* ws  = (float*)d_ws;
    float* out = (float*)d_out;

    hipLaunchKernelGGL(precompute_taps, dim3((14 * 5 * NF + 255) / 256), dim3(256), 0, stream,
                       emb, cw[0], cw[1], cw[2], cw[3], ws);

    hipLaunchKernelGGL(precompute_windows, dim3((NWIN_TOTAL * NF + 255) / 256), dim3(256), 0, stream,
                       cb[0], aw[0], ab[0],
                       cb[1], aw[1], ab[1],
                       cb[2], aw[2], ab[2],
                       cb[3], aw[3], ab[3],
                       ws);

    hipLaunchKernelGGL(build_combined, dim3((3125 * 16 + 255) / 256), dim3(256), 0, stream,
                       ws);

    hipLaunchKernelGGL(fused_main, dim3(BATCH), dim3(256), 0, stream,
                       xidx, ws, projw, projb, gm, bt, out);
}